// Round 1
// baseline (263.737 us; speedup 1.0000x reference)
//
#include <hip/hip_runtime.h>

// Hierarchical sparse attention (binary tree), MI355X gfx950.
// B=4, S=4096, H=8, D=64, f32. Wave(64)=one node/query, lane=dim.

#define S 4096
#define H 8
#define D 64
#define B 4
#define NINT 4094   // internal nodes per (b,h): levels 1..11 (root unused)
#define NBH 32      // B*H
#define SCALE 0.125f

// Build one tree level: parent = reduce(child pair).
// Child addressing: addr = b*cb_b + h*cb_h + cbase + childIdx*cstride + lane
//   leaves  : cb_b=S*H*D, cb_h=D,     cbase=0,        cstride=H*D
//   internal: cb_b=H*NINT*D, cb_h=NINT*D, cbase=off*D, cstride=D
__global__ __launch_bounds__(256) void tree_build(
    const float* __restrict__ kc, const float* __restrict__ vc,
    float* __restrict__ kt, float* __restrict__ vt,
    int nn, int lognn, int cb_b, int cb_h, int cbase, int cstride, int poff)
{
    int t = blockIdx.x * 256 + threadIdx.x;
    int lane = t & 63;
    int w = t >> 6;
    if (w >= NBH * nn) return;
    int j  = w & (nn - 1);
    int bh = w >> lognn;
    int b = bh >> 3, h = bh & 7;

    int a0 = b * cb_b + h * cb_h + cbase + (2 * j) * cstride + lane;
    int a1 = a0 + cstride;
    float k0 = kc[a0], k1 = kc[a1];
    float v0 = vc[a0], v1 = vc[a1];

    float kp = 0.5f * (k0 + k1);
    float vm = 0.5f * (v0 + v1);
    float pss = kp * kp, p0 = kp * k0, p1 = kp * k1;
#pragma unroll
    for (int off = 32; off; off >>= 1) {
        pss += __shfl_xor(pss, off);
        p0  += __shfl_xor(p0,  off);
        p1  += __shfl_xor(p1,  off);
    }
    float ss = pss * SCALE, s0 = p0 * SCALE, s1 = p1 * SCALE;
    float m  = fmaxf(ss, fmaxf(s0, s1));
    float es = __expf(ss - m), e0 = __expf(s0 - m), e1 = __expf(s1 - m);
    float inv = 1.0f / (es + e0 + e1 + 1e-9f);
    float vp = (es * vm + e0 * v0 + e1 * v1) * inv;

    int p = ((bh * NINT + poff + j) << 6) + lane;
    kt[p] = kp;
    vt[p] = vp;
}

// One wave per query (b,s,h). Active level l iff bit l of s set.
__global__ __launch_bounds__(256) void attn(
    const float* __restrict__ q, const float* __restrict__ k,
    const float* __restrict__ v,
    const float* __restrict__ kt, const float* __restrict__ vt,
    float* __restrict__ out)
{
    int t = blockIdx.x * 256 + threadIdx.x;
    int lane = t & 63;
    int w = t >> 6;            // (bh<<12) | s
    int s  = w & (S - 1);
    int bh = w >> 12;
    int b = bh >> 3, h = bh & 7;
    int qa = b * (S * H * D) + s * (H * D) + h * D + lane;

    float qv = q[qa], kv = k[qa], vv = v[qa];
    float ps = qv * kv;
#pragma unroll
    for (int off = 32; off; off >>= 1) ps += __shfl_xor(ps, off);
    float ss = ps * SCALE;

    float sc[12], vcr[12];
    int tb = bh * NINT;
#pragma unroll
    for (int l = 0; l < 12; ++l) {
        if ((s >> l) & 1) {            // wave-uniform branch
            float kcv, vcv;
            if (l == 0) {
                int a = qa - H * D;    // sibling leaf s-1 (s odd here)
                kcv = k[a]; vcv = v[a];
            } else {
                int node = (S - (S >> (l - 1))) + ((s >> l) ^ 1);
                int a = ((tb + node) << 6) + lane;
                kcv = kt[a]; vcv = vt[a];
            }
            float p = qv * kcv;
#pragma unroll
            for (int off = 32; off; off >>= 1) p += __shfl_xor(p, off);
            sc[l]  = p * SCALE;
            vcr[l] = vcv;
        } else {
            sc[l]  = -1e30f;
            vcr[l] = 0.0f;
        }
    }

    float m = ss;
#pragma unroll
    for (int l = 0; l < 12; ++l) m = fmaxf(m, sc[l]);
    float es = __expf(ss - m);
    float denom = es;
    float acc = es * vv;
#pragma unroll
    for (int l = 0; l < 12; ++l) {
        float e = __expf(sc[l] - m);   // inactive: exp(-1e30-m)=0
        denom += e;
        acc += e * vcr[l];
    }
    out[qa] = acc / denom;
}

extern "C" void kernel_launch(void* const* d_in, const int* in_sizes, int n_in,
                              void* d_out, int out_size, void* d_ws, size_t ws_size,
                              hipStream_t stream) {
    const float* q = (const float*)d_in[0];
    const float* k = (const float*)d_in[1];
    const float* v = (const float*)d_in[2];
    float* outp = (float*)d_out;
    float* kt = (float*)d_ws;                       // 32*4094*64 f32 = 33.5 MB
    float* vt = kt + (size_t)NBH * NINT * D;        // +33.5 MB (ws >= 67MB)

    // Level 1: children are leaves (k, v)
    {
        int nn = S >> 1;                            // 2048
        int threads = NBH * nn * 64;
        hipLaunchKernelGGL(tree_build, dim3(threads / 256), dim3(256), 0, stream,
                           k, v, kt, vt, nn, 11, S * H * D, D, 0, H * D, 0);
    }
    // Levels 2..11: children are internal nodes
    int prev_off = 0, nn = S >> 1;
    for (int l = 2; l <= 11; ++l) {
        int cur_off = prev_off + nn;                // off_int(l)
        nn >>= 1;                                   // S >> l
        int lognn = 12 - l;
        int threads = NBH * nn * 64;
        int blocks = (threads + 255) / 256;
        hipLaunchKernelGGL(tree_build, dim3(blocks), dim3(256), 0, stream,
                           kt, vt, kt, vt, nn, lognn,
                           H * NINT * D, NINT * D, prev_off * D, D, cur_off);
        prev_off = cur_off;
    }
    // Attention
    {
        int threads = B * S * H * 64;               // 8,388,608
        hipLaunchKernelGGL(attn, dim3(threads / 256), dim3(256), 0, stream,
                           q, k, v, kt, vt, outp);
    }
}

// Round 2
// 181.247 us; speedup vs baseline: 1.4551x; 1.4551x over previous
//
#include <hip/hip_runtime.h>

// Hierarchical sparse attention (binary tree), MI355X gfx950.
// B=4, S=4096, H=8, D=64, f32.
// Wave layout: 4 items x 16 lanes, lane holds 4 dims (float4).

#define S 4096
#define H 8
#define D 64
#define B 4
#define NINT 4094   // internal nodes per (b,h): levels 1..11 (root unused)
#define NBH 32      // B*H
#define SCALE 0.125f

__device__ inline float red16(float x) {
    x += __shfl_xor(x, 1);
    x += __shfl_xor(x, 2);
    x += __shfl_xor(x, 4);
    x += __shfl_xor(x, 8);
    return x;
}

__device__ inline float dot4(const float4 a, const float4 b) {
    return a.x * b.x + a.y * b.y + a.z * b.z + a.w * b.w;
}

// parent(k,v) from two children: softmax-weighted merge (16-lane reduce).
__device__ inline void combine(const float4 k0, const float4 k1,
                               const float4 v0, const float4 v1,
                               float4& kp, float4& vp) {
    kp.x = 0.5f * (k0.x + k1.x);
    kp.y = 0.5f * (k0.y + k1.y);
    kp.z = 0.5f * (k0.z + k1.z);
    kp.w = 0.5f * (k0.w + k1.w);
    float pss = red16(dot4(kp, kp)) * SCALE;
    float p0  = red16(dot4(kp, k0)) * SCALE;
    float p1  = red16(dot4(kp, k1)) * SCALE;
    float m  = fmaxf(pss, fmaxf(p0, p1));
    float es = __expf(pss - m), e0 = __expf(p0 - m), e1 = __expf(p1 - m);
    float inv = 1.0f / (es + e0 + e1 + 1e-9f);
    float h = 0.5f * es;
    vp.x = ((h + e0) * v0.x + (h + e1) * v1.x) * inv;
    vp.y = ((h + e0) * v0.y + (h + e1) * v1.y) * inv;
    vp.z = ((h + e0) * v0.z + (h + e1) * v1.z) * inv;
    vp.w = ((h + e0) * v0.w + (h + e1) * v1.w) * inv;
}

// Levels 1..7: one block per (bh, 128-leaf chunk); children staged in LDS.
__global__ __launch_bounds__(256) void tree_chunk(
    const float* __restrict__ k, const float* __restrict__ v,
    float* __restrict__ kt, float* __restrict__ vt)
{
    __shared__ float lk[127 * 64];
    __shared__ float lv[127 * 64];
    const int t = threadIdx.x;
    const int sub = t & 15;
    const int pg = t >> 4;           // 0..15 parent-groups
    const int blk = blockIdx.x;
    const int c = blk & 31;          // chunk
    const int bh = blk >> 5;
    const int b = bh >> 3, h = bh & 7;

    // level 1: 64 parents, children = global leaves
    for (int j = pg; j < 64; j += 16) {
        int s0 = c * 128 + 2 * j;
        size_t a0 = ((((size_t)b * S + s0) * H + h) * D) + sub * 4;
        float4 k0 = *(const float4*)(k + a0);
        float4 k1 = *(const float4*)(k + a0 + H * D);
        float4 v0 = *(const float4*)(v + a0);
        float4 v1 = *(const float4*)(v + a0 + H * D);
        float4 kp, vp;
        combine(k0, k1, v0, v1, kp, vp);
        *(float4*)(lk + j * 64 + sub * 4) = kp;
        *(float4*)(lv + j * 64 + sub * 4) = vp;
        size_t g = ((size_t)bh * NINT + c * 64 + j) * 64 + sub * 4;
        *(float4*)(kt + g) = kp;
        *(float4*)(vt + g) = vp;
    }
    __syncthreads();

    int coff = 0;                    // LDS node offset of child level
    for (int l = 2; l <= 7; ++l) {
        int np = 128 >> l;           // parents in chunk at this level
        int poff = coff + (128 >> (l - 1));
        int goff = S - (S >> (l - 1));
        for (int j = pg; j < np; j += 16) {
            float4 k0 = *(const float4*)(lk + (coff + 2 * j) * 64 + sub * 4);
            float4 k1 = *(const float4*)(lk + (coff + 2 * j + 1) * 64 + sub * 4);
            float4 v0 = *(const float4*)(lv + (coff + 2 * j) * 64 + sub * 4);
            float4 v1 = *(const float4*)(lv + (coff + 2 * j + 1) * 64 + sub * 4);
            float4 kp, vp;
            combine(k0, k1, v0, v1, kp, vp);
            *(float4*)(lk + (poff + j) * 64 + sub * 4) = kp;
            *(float4*)(lv + (poff + j) * 64 + sub * 4) = vp;
            size_t g = ((size_t)bh * NINT + goff + c * np + j) * 64 + sub * 4;
            *(float4*)(kt + g) = kp;
            *(float4*)(vt + g) = vp;
        }
        __syncthreads();
        coff = poff;
    }
}

// Levels 8..11: one block per bh.
__global__ __launch_bounds__(256) void tree_top(
    float* __restrict__ kt, float* __restrict__ vt)
{
    __shared__ float lk[62 * 64];
    __shared__ float lv[62 * 64];
    const int t = threadIdx.x;
    const int sub = t & 15;
    const int pg = t >> 4;
    const int bh = blockIdx.x;

    // load level 7 (32 nodes) into LDS[0..31]
    for (int i = t; i < 512; i += 256) {
        size_t g = ((size_t)bh * NINT + (S - (S >> 6))) * 64 + i * 4;
        *(float4*)(lk + i * 4) = *(const float4*)(kt + g);
        *(float4*)(lv + i * 4) = *(const float4*)(vt + g);
    }
    __syncthreads();

    int coff = 0, cn = 32;
    for (int l = 8; l <= 11; ++l) {
        int np = cn >> 1;
        int poff = coff + cn;
        int goff = S - (S >> (l - 1));
        if (pg < np) {
            int j = pg;
            float4 k0 = *(const float4*)(lk + (coff + 2 * j) * 64 + sub * 4);
            float4 k1 = *(const float4*)(lk + (coff + 2 * j + 1) * 64 + sub * 4);
            float4 v0 = *(const float4*)(lv + (coff + 2 * j) * 64 + sub * 4);
            float4 v1 = *(const float4*)(lv + (coff + 2 * j + 1) * 64 + sub * 4);
            float4 kp, vp;
            combine(k0, k1, v0, v1, kp, vp);
            *(float4*)(lk + (poff + j) * 64 + sub * 4) = kp;
            *(float4*)(lv + (poff + j) * 64 + sub * 4) = vp;
            size_t g = ((size_t)bh * NINT + goff + j) * 64 + sub * 4;
            *(float4*)(kt + g) = kp;
            *(float4*)(vt + g) = vp;
        }
        __syncthreads();
        coff = poff; cn = np;
    }
}

// Wave = 4 heads of one query s (wave-uniform levels), lane = 4 dims.
__global__ __launch_bounds__(256) void attn(
    const float* __restrict__ q, const float* __restrict__ k,
    const float* __restrict__ v,
    const float* __restrict__ kt, const float* __restrict__ vt,
    float* __restrict__ out)
{
    int t = blockIdx.x * 256 + threadIdx.x;
    int lane = t & 63;
    int sub = lane & 15;
    int qi = lane >> 4;
    int w = t >> 6;
    int hg = w & 1;
    int s = (w >> 1) & (S - 1);
    int b = w >> 13;
    int h = hg * 4 + qi;
    int bh = b * 8 + h;
    size_t qa = ((((size_t)b * S + s) * H + h) * D) + sub * 4;

    float4 q4 = *(const float4*)(q + qa);
    float4 k4 = *(const float4*)(k + qa);
    float4 v4 = *(const float4*)(v + qa);
    float ss = red16(dot4(q4, k4)) * SCALE;

    float m = ss, denom = 1.0f;
    float4 acc = v4;
    size_t tb = (size_t)bh * NINT;

#pragma unroll
    for (int l = 0; l < 12; ++l) {
        if ((s >> l) & 1) {          // wave-uniform (s same across wave)
            float4 kc, vc;
            if (l == 0) {
                kc = *(const float4*)(k + qa - H * D);
                vc = *(const float4*)(v + qa - H * D);
            } else {
                int node = (S - (S >> (l - 1))) + ((s >> l) ^ 1);
                size_t a = (tb + node) * 64 + sub * 4;
                kc = *(const float4*)(kt + a);
                vc = *(const float4*)(vt + a);
            }
            float sc = red16(dot4(q4, kc)) * SCALE;
            float nm = fmaxf(m, sc);
            float c1 = __expf(m - nm);
            float e  = __expf(sc - nm);
            denom = denom * c1 + e;
            acc.x = acc.x * c1 + e * vc.x;
            acc.y = acc.y * c1 + e * vc.y;
            acc.z = acc.z * c1 + e * vc.z;
            acc.w = acc.w * c1 + e * vc.w;
            m = nm;
        }
    }
    float inv = 1.0f / denom;
    float4 o;
    o.x = acc.x * inv; o.y = acc.y * inv; o.z = acc.z * inv; o.w = acc.w * inv;
    *(float4*)(out + qa) = o;
}

extern "C" void kernel_launch(void* const* d_in, const int* in_sizes, int n_in,
                              void* d_out, int out_size, void* d_ws, size_t ws_size,
                              hipStream_t stream) {
    const float* q = (const float*)d_in[0];
    const float* k = (const float*)d_in[1];
    const float* v = (const float*)d_in[2];
    float* outp = (float*)d_out;
    float* kt = (float*)d_ws;                       // 32*4094*64 f32 = 33.5 MB
    float* vt = kt + (size_t)NBH * NINT * D;        // +33.5 MB

    hipLaunchKernelGGL(tree_chunk, dim3(NBH * 32), dim3(256), 0, stream,
                       k, v, kt, vt);
    hipLaunchKernelGGL(tree_top, dim3(NBH), dim3(256), 0, stream, kt, vt);
    hipLaunchKernelGGL(attn, dim3((B * S * 2 * 64) / 256), dim3(256), 0, stream,
                       q, k, v, kt, vt, outp);
}

// Round 3
// 175.748 us; speedup vs baseline: 1.5007x; 1.0313x over previous
//
#include <hip/hip_runtime.h>

// Hierarchical sparse attention (binary tree), MI355X gfx950.
// B=4, S=4096, H=8, D=64, f32.
// Wave layout: 4 items x 16 lanes, lane holds 4 dims (float4).

#define S 4096
#define H 8
#define D 64
#define B 4
#define NINT 4094   // internal nodes per (b,h): levels 1..11 (root unused)
#define NBH 32      // B*H
#define SCALE 0.125f

__device__ inline float red16(float x) {
    x += __shfl_xor(x, 1);
    x += __shfl_xor(x, 2);
    x += __shfl_xor(x, 4);
    x += __shfl_xor(x, 8);
    return x;
}

__device__ inline float dot4(const float4 a, const float4 b) {
    return a.x * b.x + a.y * b.y + a.z * b.z + a.w * b.w;
}

// parent(k,v) from two children: softmax-weighted merge (16-lane reduce).
__device__ inline void combine(const float4 k0, const float4 k1,
                               const float4 v0, const float4 v1,
                               float4& kp, float4& vp) {
    kp.x = 0.5f * (k0.x + k1.x);
    kp.y = 0.5f * (k0.y + k1.y);
    kp.z = 0.5f * (k0.z + k1.z);
    kp.w = 0.5f * (k0.w + k1.w);
    float pss = red16(dot4(kp, kp)) * SCALE;
    float p0  = red16(dot4(kp, k0)) * SCALE;
    float p1  = red16(dot4(kp, k1)) * SCALE;
    float m  = fmaxf(pss, fmaxf(p0, p1));
    float es = __expf(pss - m), e0 = __expf(p0 - m), e1 = __expf(p1 - m);
    float inv = 1.0f / (es + e0 + e1 + 1e-9f);
    float h = 0.5f * es;
    vp.x = ((h + e0) * v0.x + (h + e1) * v1.x) * inv;
    vp.y = ((h + e0) * v0.y + (h + e1) * v1.y) * inv;
    vp.z = ((h + e0) * v0.z + (h + e1) * v1.z) * inv;
    vp.w = ((h + e0) * v0.w + (h + e1) * v1.w) * inv;
}

// Levels 1..6: one block per (bh, 64-leaf chunk); ping-pong LDS (24.5 KB).
__global__ __launch_bounds__(256) void tree_chunk(
    const float* __restrict__ k, const float* __restrict__ v,
    float* __restrict__ kt, float* __restrict__ vt)
{
    __shared__ float lkA[32 * 64], lvA[32 * 64];
    __shared__ float lkB[16 * 64], lvB[16 * 64];
    const int t = threadIdx.x;
    const int sub = t & 15;
    const int pg = t >> 4;           // 0..15
    const int blk = blockIdx.x;
    const int c = blk & 63;          // 64-leaf chunk
    const int bh = blk >> 6;
    const int b = bh >> 3, h = bh & 7;

    // level 1: 32 parents, children = global leaves
#pragma unroll
    for (int r = 0; r < 2; ++r) {
        int j = pg + r * 16;
        int s0 = c * 64 + 2 * j;
        size_t a0 = ((((size_t)b * S + s0) * H + h) * D) + sub * 4;
        float4 k0 = *(const float4*)(k + a0);
        float4 k1 = *(const float4*)(k + a0 + H * D);
        float4 v0 = *(const float4*)(v + a0);
        float4 v1 = *(const float4*)(v + a0 + H * D);
        float4 kp, vp;
        combine(k0, k1, v0, v1, kp, vp);
        *(float4*)(lkA + j * 64 + sub * 4) = kp;
        *(float4*)(lvA + j * 64 + sub * 4) = vp;
        size_t g = ((size_t)bh * NINT + c * 32 + j) * 64 + sub * 4;
        *(float4*)(kt + g) = kp;
        *(float4*)(vt + g) = vp;
    }
    __syncthreads();

    float *sk = lkA, *sv = lvA, *dk = lkB, *dv = lvB;
#pragma unroll
    for (int l = 2; l <= 6; ++l) {
        int np = 64 >> l;            // 16,8,4,2,1
        int goff = S - (S >> (l - 1));
        if (pg < np) {
            int j = pg;
            float4 k0 = *(const float4*)(sk + (2 * j) * 64 + sub * 4);
            float4 k1 = *(const float4*)(sk + (2 * j + 1) * 64 + sub * 4);
            float4 v0 = *(const float4*)(sv + (2 * j) * 64 + sub * 4);
            float4 v1 = *(const float4*)(sv + (2 * j + 1) * 64 + sub * 4);
            float4 kp, vp;
            combine(k0, k1, v0, v1, kp, vp);
            if (l < 6) {
                *(float4*)(dk + j * 64 + sub * 4) = kp;
                *(float4*)(dv + j * 64 + sub * 4) = vp;
            }
            size_t g = ((size_t)bh * NINT + goff + c * np + j) * 64 + sub * 4;
            *(float4*)(kt + g) = kp;
            *(float4*)(vt + g) = vp;
        }
        __syncthreads();
        float* tp;
        tp = sk; sk = dk; dk = tp;
        tp = sv; sv = dv; dv = tp;
    }
}

// Levels 7..11: one block per bh, from the 64 level-6 nodes.
__global__ __launch_bounds__(256) void tree_top(
    float* __restrict__ kt, float* __restrict__ vt)
{
    __shared__ float lkA[64 * 64], lvA[64 * 64];
    __shared__ float lkB[32 * 64], lvB[32 * 64];
    const int t = threadIdx.x;
    const int sub = t & 15;
    const int pg = t >> 4;
    const int bh = blockIdx.x;

    // load level 6 (64 nodes, off=3968) into A
    for (int i = t; i < 1024; i += 256) {
        size_t g = ((size_t)bh * NINT + 3968) * 64 + i * 4;
        *(float4*)(lkA + i * 4) = *(const float4*)(kt + g);
        *(float4*)(lvA + i * 4) = *(const float4*)(vt + g);
    }
    __syncthreads();

    float *sk = lkA, *sv = lvA, *dk = lkB, *dv = lvB;
    int cn = 64;
#pragma unroll
    for (int l = 7; l <= 11; ++l) {
        int np = cn >> 1;            // 32,16,8,4,2
        int goff = S - (S >> (l - 1));
        for (int j = pg; j < np; j += 16) {
            float4 k0 = *(const float4*)(sk + (2 * j) * 64 + sub * 4);
            float4 k1 = *(const float4*)(sk + (2 * j + 1) * 64 + sub * 4);
            float4 v0 = *(const float4*)(sv + (2 * j) * 64 + sub * 4);
            float4 v1 = *(const float4*)(sv + (2 * j + 1) * 64 + sub * 4);
            float4 kp, vp;
            combine(k0, k1, v0, v1, kp, vp);
            if (l < 11) {
                *(float4*)(dk + j * 64 + sub * 4) = kp;
                *(float4*)(dv + j * 64 + sub * 4) = vp;
            }
            size_t g = ((size_t)bh * NINT + goff + j) * 64 + sub * 4;
            *(float4*)(kt + g) = kp;
            *(float4*)(vt + g) = vp;
        }
        __syncthreads();
        float* tp;
        tp = sk; sk = dk; dk = tp;
        tp = sv; sv = dv; dv = tp;
        cn = np;
    }
}

// Wave = 4 heads of one query s (wave-uniform levels), lane = 4 dims.
// Batch-score form: all loads up front, independent reductions, one softmax.
__global__ __launch_bounds__(256) void attn(
    const float* __restrict__ q, const float* __restrict__ k,
    const float* __restrict__ v,
    const float* __restrict__ kt, const float* __restrict__ vt,
    float* __restrict__ out)
{
    int t = blockIdx.x * 256 + threadIdx.x;
    int lane = t & 63;
    int sub = lane & 15;
    int qi = lane >> 4;
    int w = t >> 6;
    int hg = w & 1;
    int s = (w >> 1) & (S - 1);
    int b = w >> 13;
    int h = hg * 4 + qi;
    int bh = b * 8 + h;
    size_t qa = ((((size_t)b * S + s) * H + h) * D) + sub * 4;

    float4 q4 = *(const float4*)(q + qa);
    float4 k4 = *(const float4*)(k + qa);
    float4 v4 = *(const float4*)(v + qa);

    float4 kc[12], vc[12];
    size_t tb = (size_t)bh * NINT;
#pragma unroll
    for (int l = 0; l < 12; ++l) {
        if ((s >> l) & 1) {          // wave-uniform
            if (l == 0) {
                kc[0] = *(const float4*)(k + qa - H * D);
                vc[0] = *(const float4*)(v + qa - H * D);
            } else {
                int node = (S - (S >> (l - 1))) + ((s >> l) ^ 1);
                size_t a = (tb + node) * 64 + sub * 4;
                kc[l] = *(const float4*)(kt + a);
                vc[l] = *(const float4*)(vt + a);
            }
        }
    }

    float ss = red16(dot4(q4, k4)) * SCALE;
    float sc[12];
#pragma unroll
    for (int l = 0; l < 12; ++l) {
        if ((s >> l) & 1) sc[l] = red16(dot4(q4, kc[l])) * SCALE;
        else              sc[l] = -1e38f;
    }

    float m = ss;
#pragma unroll
    for (int l = 0; l < 12; ++l) m = fmaxf(m, sc[l]);

    float es = __expf(ss - m);
    float denom = es;
    float4 acc;
    acc.x = es * v4.x; acc.y = es * v4.y; acc.z = es * v4.z; acc.w = es * v4.w;
#pragma unroll
    for (int l = 0; l < 12; ++l) {
        if ((s >> l) & 1) {          // wave-uniform; guards 0*garbage NaN
            float e = __expf(sc[l] - m);
            denom += e;
            acc.x += e * vc[l].x;
            acc.y += e * vc[l].y;
            acc.z += e * vc[l].z;
            acc.w += e * vc[l].w;
        }
    }
    float inv = 1.0f / denom;
    float4 o;
    o.x = acc.x * inv; o.y = acc.y * inv; o.z = acc.z * inv; o.w = acc.w * inv;
    *(float4*)(out + qa) = o;
}

extern "C" void kernel_launch(void* const* d_in, const int* in_sizes, int n_in,
                              void* d_out, int out_size, void* d_ws, size_t ws_size,
                              hipStream_t stream) {
    const float* q = (const float*)d_in[0];
    const float* k = (const float*)d_in[1];
    const float* v = (const float*)d_in[2];
    float* outp = (float*)d_out;
    float* kt = (float*)d_ws;                       // 32*4094*64 f32 = 33.5 MB
    float* vt = kt + (size_t)NBH * NINT * D;        // +33.5 MB

    hipLaunchKernelGGL(tree_chunk, dim3(NBH * 64), dim3(256), 0, stream,
                       k, v, kt, vt);
    hipLaunchKernelGGL(tree_top, dim3(NBH), dim3(256), 0, stream, kt, vt);
    hipLaunchKernelGGL(attn, dim3((B * S * 2 * 64) / 256), dim3(256), 0, stream,
                       q, k, v, kt, vt, outp);
}